// Round 18
// baseline (289.215 us; speedup 1.0000x reference)
//
#include <hip/hip_runtime.h>
#include <hip/hip_fp16.h>

#define HID 64
#define NGRAPHS 256
#define CHUNK 8192        // edges per scatter chunk
#define BKTSZ 512         // nodes per coarse bucket
#define BKTSH 9
#define PSH 17            // src fits in 17 bits (N <= 131072)
#define PMASK 0x1FFFF
#define CAP 128           // slot capacity per (bucket,chunk); Poisson l=42,
                          // P(>128) ~ 1e-25/cell -> no overflow (fixed data)

typedef _Float16 half8 __attribute__((ext_vector_type(8)));
typedef float f32x4 __attribute__((ext_vector_type(4)));

// MEASURED LAWS (R1-R17):
//  - scattered device-scope atomics/stores write through ~64B lines at
//    ~0.9 TB/s; same-line fp32 atomics ~15 G/s (R1 pool) -> LDS counting
//    sort; NEVER scattered-atomic accumulation.
//  - grid.sync() coop barrier ~100us at full grid (R13) -> discrete
//    launches (~6-7us/boundary); minimize launch COUNT structurally.
//  - R14: narrow-grid fusion serializes wide phases; R17: same-grid
//    fusion (agg+gemm) wins. R15: >8-wide gather unroll regresses.

// ---- P0: scatter+hist fused: slots at (bkt*nchunk+chunk)*CAP ------------
// prepW in blocks 0-1. Rank counters lc[] double as the histogram H.

__global__ __launch_bounds__(256) void k_scatter_hist(
        const int* __restrict__ src, const int* __restrict__ dst,
        const float* __restrict__ W2, const float* __restrict__ W3,
        __half* __restrict__ Wf2, __half* __restrict__ Wf3,
        int* __restrict__ packed, int* __restrict__ H,
        int e, int nbkt, int nchunk) {
    __shared__ int lc[256];
    const int t = threadIdx.x, b = blockIdx.x;
    const int gtid = b * 256 + t;
    if (gtid < 512) {       // W fragment repack: 16x16x32-f16 B layout
        int p = gtid;
        int kt = p >> 8, c = (p >> 6) & 3, lane = p & 63;
        int quad = lane >> 4, m = lane & 15;
#pragma unroll
        for (int j = 0; j < 8; ++j) {
            int k = kt * 32 + quad * 8 + j;
            int ch = c * 16 + m;
            Wf2[(size_t)p * 8 + j] = __float2half(W2[k * HID + ch]);
            Wf3[(size_t)p * 8 + j] = __float2half(W3[k * HID + ch]);
        }
    }
    for (int i = t; i < nbkt; i += 256) lc[i] = 0;
    __syncthreads();
#pragma unroll
    for (int it = 0; it < CHUNK / 1024; ++it) {
        int idx = b * CHUNK + it * 1024 + t * 4;
        if (idx + 3 < e) {
            int4 d = *(const int4*)(dst + idx);
            int4 s = *(const int4*)(src + idx);
            int b0 = d.x >> BKTSH, b1 = d.y >> BKTSH;
            int b2 = d.z >> BKTSH, b3 = d.w >> BKTSH;
            int r0 = atomicAdd(&lc[b0], 1);
            int r1 = atomicAdd(&lc[b1], 1);
            int r2 = atomicAdd(&lc[b2], 1);
            int r3 = atomicAdd(&lc[b3], 1);
            packed[(b0 * nchunk + b) * CAP + r0] = s.x | ((d.x & (BKTSZ - 1)) << PSH);
            packed[(b1 * nchunk + b) * CAP + r1] = s.y | ((d.y & (BKTSZ - 1)) << PSH);
            packed[(b2 * nchunk + b) * CAP + r2] = s.z | ((d.z & (BKTSZ - 1)) << PSH);
            packed[(b3 * nchunk + b) * CAP + r3] = s.w | ((d.w & (BKTSZ - 1)) << PSH);
        } else {
            for (int i = idx; i < e && i < idx + 4; ++i) {
                int dd = dst[i];
                int bk = dd >> BKTSH;
                int r = atomicAdd(&lc[bk], 1);
                packed[(bk * nchunk + b) * CAP + r] = src[i] | ((dd & (BKTSZ - 1)) << PSH);
            }
        }
    }
    __syncthreads();
    for (int i = t; i < nbkt; i += 256) H[i * nchunk + b] = lc[i];
}

// ---- P1: per-bucket CSR build from slotted packed -----------------------
// segStart = coop sum of H[0..bkt*nchunk); per-chunk prefix in LDS;
// per-edge chunk lookup via LDS binary search.

__global__ __launch_bounds__(256) void k_csr_build(
        const int* __restrict__ packed, const int* __restrict__ H,
        int* __restrict__ rowptr, float* __restrict__ dinv,
        int* __restrict__ csr, int e, int n, int nbkt, int nchunk) {
    __shared__ int cnt[BKTSZ];
    __shared__ int pref[BKTSZ];
    __shared__ int ssum[256];
    __shared__ int cnt2[BKTSZ];
    __shared__ int hcnt[160];
    __shared__ int cpre[161];
    __shared__ int segsh[256];
    const int t = threadIdx.x, bkt = blockIdx.x;

    // segStart: cooperative sum of all earlier buckets' chunk counts
    {
        int lim = bkt * nchunk;
        int part = 0;
        for (int i = t; i < lim; i += 256) part += H[i];
        segsh[t] = part;
        __syncthreads();
#pragma unroll
        for (int off = 128; off >= 1; off >>= 1) {
            if (t < off) segsh[t] += segsh[t + off];
            __syncthreads();
        }
    }
    const int segStart = segsh[0];

    if (t < nchunk) hcnt[t] = H[bkt * nchunk + t];
    cnt[t] = 0; cnt[t + 256] = 0;
    cnt2[t] = 0; cnt2[t + 256] = 0;
    if (bkt == 0 && t == 0) rowptr[n] = e;
    __syncthreads();
    if (t == 0) {
        int run = 0;
        for (int c = 0; c < nchunk; ++c) { cpre[c] = run; run += hcnt[c]; }
        cpre[nchunk] = run;
    }
    __syncthreads();
    const int total = cpre[nchunk];

    // pass 1: per-node counts
    for (int el = t; el < total; el += 256) {
        int lo = 0, hi = nchunk - 1;
        while (lo < hi) { int mid = (lo + hi + 1) >> 1; if (cpre[mid] <= el) lo = mid; else hi = mid - 1; }
        int pk = packed[(bkt * nchunk + lo) * CAP + (el - cpre[lo])];
        atomicAdd(&cnt[(pk >> PSH) & (BKTSZ - 1)], 1);
    }
    __syncthreads();
    // exclusive scan of cnt[512] (pair per thread)
    int a0 = cnt[2 * t], a1 = cnt[2 * t + 1];
    int s = a0 + a1;
    ssum[t] = s;
    __syncthreads();
#pragma unroll
    for (int off = 1; off < 256; off <<= 1) {
        int add = (t >= off) ? ssum[t - off] : 0;
        __syncthreads();
        ssum[t] += add;
        __syncthreads();
    }
    int p = ssum[t] - s;
    pref[2 * t] = p;
    pref[2 * t + 1] = p + a0;
    __syncthreads();
    for (int i = t; i < BKTSZ; i += 256) {
        int node = bkt * BKTSZ + i;
        if (node < n) {
            rowptr[node] = segStart + pref[i];
            dinv[node] = rsqrtf((float)(cnt[i] + 1));   // +1 self-loop
        }
    }
    // pass 2: place edges
    for (int el = t; el < total; el += 256) {
        int lo = 0, hi = nchunk - 1;
        while (lo < hi) { int mid = (lo + hi + 1) >> 1; if (cpre[mid] <= el) lo = mid; else hi = mid - 1; }
        int pk = packed[(bkt * nchunk + lo) * CAP + (el - cpre[lo])];
        int ld = (pk >> PSH) & (BKTSZ - 1);
        int r = atomicAdd(&cnt2[ld], 1);
        csr[segStart + pref[ld] + r] = pk & PMASK;
    }
}

// ---- layer-1 gemm (K=7, fp32 in, WIDE grid): h' = (x @ W1) * dinv -------

__global__ __launch_bounds__(256) void k_gemm7(
        const float* __restrict__ act, const float* __restrict__ W,
        const float* __restrict__ dinv, __half* __restrict__ h, int n_nodes) {
    __shared__ float Wsh[7 * HID];
    __shared__ float Ash[16 * 7];
    const int t = threadIdx.x;
    const int n0 = blockIdx.x * 16;

    for (int i = t; i < 7 * HID; i += 256) Wsh[i] = W[i];
    const long long lim = (long long)(n_nodes - n0) * 7;
    for (int i = t; i < 16 * 7; i += 256)
        Ash[i] = (i < lim) ? act[(size_t)n0 * 7 + i] : 0.0f;
    __syncthreads();

    const int c = t & 63;
    const int g = t >> 6;
    float acc[4] = {0.0f, 0.0f, 0.0f, 0.0f};
#pragma unroll
    for (int k = 0; k < 7; k++) {
        float w = Wsh[k * HID + c];
#pragma unroll
        for (int i = 0; i < 4; i++) acc[i] += Ash[(g * 4 + i) * 7 + k] * w;
    }
#pragma unroll
    for (int i = 0; i < 4; i++) {
        int n = n0 + g * 4 + i;
        if (n < n_nodes) h[(size_t)n * HID + c] = __float2half(acc[i] * dinv[n]);
    }
}

__device__ __forceinline__ float4 h4_to_f4(int2 raw) {
    __half2 p0 = *(__half2*)&raw.x;
    __half2 p1 = *(__half2*)&raw.y;
    float2 f0 = __half22float2(p0);
    float2 f1 = __half22float2(p1);
    return make_float4(f0.x, f0.y, f1.x, f1.y);
}

// ---- FUSED aggregate + MFMA gemm (layers 1->2, 2->3) --------------------

__global__ __launch_bounds__(256) void k_agg_gemm(
        const int* __restrict__ rowptr, const int* __restrict__ csr,
        const __half* __restrict__ h, const float* __restrict__ b,
        const float* __restrict__ dinv, const __half* __restrict__ Wf,
        __half* __restrict__ hout, int n_nodes) {
    __shared__ __half act[16 * 72];
    const int t = threadIdx.x;
    const int n0 = blockIdx.x * 16;
    const int nl = t >> 4;          // local node 0..15
    const int node = n0 + nl;
    const int l16 = t & 15;
    const int2* h8 = (const int2*)h;
    const float4* b4 = (const float4*)b;

    float4 av = make_float4(0.0f, 0.0f, 0.0f, 0.0f);
    if (node < n_nodes) {
        int beg = rowptr[node], end = rowptr[node + 1];
        float dv = dinv[node];
        float4 inner = h4_to_f4(h8[(size_t)node * 16 + l16]);   // self h'
        int j = beg;
        for (; j + 7 < end; j += 8) {              // 8 outstanding gathers
            int s[8];
#pragma unroll
            for (int q = 0; q < 8; ++q) s[q] = csr[j + q];
            int2 r[8];
#pragma unroll
            for (int q = 0; q < 8; ++q) r[q] = h8[(size_t)s[q] * 16 + l16];
#pragma unroll
            for (int q = 0; q < 8; ++q) {
                float4 v = h4_to_f4(r[q]);
                inner.x += v.x; inner.y += v.y; inner.z += v.z; inner.w += v.w;
            }
        }
        for (; j + 3 < end; j += 4) {
            int s0 = csr[j], s1 = csr[j + 1], s2 = csr[j + 2], s3 = csr[j + 3];
            float4 v0 = h4_to_f4(h8[(size_t)s0 * 16 + l16]);
            float4 v1 = h4_to_f4(h8[(size_t)s1 * 16 + l16]);
            float4 v2 = h4_to_f4(h8[(size_t)s2 * 16 + l16]);
            float4 v3 = h4_to_f4(h8[(size_t)s3 * 16 + l16]);
            inner.x += v0.x + v1.x + v2.x + v3.x;
            inner.y += v0.y + v1.y + v2.y + v3.y;
            inner.z += v0.z + v1.z + v2.z + v3.z;
            inner.w += v0.w + v1.w + v2.w + v3.w;
        }
        for (; j < end; j++) {
            float4 v = h4_to_f4(h8[(size_t)csr[j] * 16 + l16]);
            inner.x += v.x; inner.y += v.y; inner.z += v.z; inner.w += v.w;
        }
        float4 bb = b4[l16];
        av.x = fmaxf(bb.x + dv * inner.x, 0.0f);   // relu(agg) = gemm input
        av.y = fmaxf(bb.y + dv * inner.y, 0.0f);
        av.z = fmaxf(bb.z + dv * inner.z, 0.0f);
        av.w = fmaxf(bb.w + dv * inner.w, 0.0f);
    }
    {   // stage act tile: row nl, cols l16*4..+3 (8B store)
        __half2 p0 = __floats2half2_rn(av.x, av.y);
        __half2 p1 = __floats2half2_rn(av.z, av.w);
        int2 pk;
        pk.x = *(int*)&p0;
        pk.y = *(int*)&p1;
        *(int2*)&act[nl * 72 + l16 * 4] = pk;
    }
    __syncthreads();

    const int wave = t >> 6, lane = t & 63;
    const int quad = lane >> 4, m = lane & 15;
    const half8* Wf8 = (const half8*)Wf;
    f32x4 acc = {0.0f, 0.0f, 0.0f, 0.0f};
#pragma unroll
    for (int kt = 0; kt < 2; ++kt) {
        half8 a = *(const half8*)&act[m * 72 + kt * 32 + quad * 8];
        half8 bv = Wf8[(kt * 4 + wave) * 64 + lane];
        acc = __builtin_amdgcn_mfma_f32_16x16x32_f16(a, bv, acc, 0, 0, 0);
    }
#pragma unroll
    for (int r = 0; r < 4; ++r) {
        int nd = n0 + quad * 4 + r;
        if (nd < n_nodes)
            hout[(size_t)nd * HID + wave * 16 + m] =
                __float2half(acc[r] * dinv[nd]);
    }
}

// ---- layer-3 aggregate (standalone; pool needs agg), fp16 out -----------

__global__ __launch_bounds__(256) void k_aggregate(
        const int* __restrict__ rowptr, const int* __restrict__ csr,
        const __half* __restrict__ h, const float* __restrict__ b,
        const float* __restrict__ dinv, __half* __restrict__ agg, int n_nodes) {
    int node = blockIdx.x * 16 + (threadIdx.x >> 4);
    int l16 = threadIdx.x & 15;
    if (node >= n_nodes) return;
    int beg = rowptr[node], end = rowptr[node + 1];
    const int2* h8 = (const int2*)h;
    const float4* b4 = (const float4*)b;
    float dv = dinv[node];
    float4 inner = h4_to_f4(h8[(size_t)node * 16 + l16]);   // self h'
    int j = beg;
    for (; j + 7 < end; j += 8) {                  // 8 outstanding gathers
        int s[8];
#pragma unroll
        for (int q = 0; q < 8; ++q) s[q] = csr[j + q];
        int2 r[8];
#pragma unroll
        for (int q = 0; q < 8; ++q) r[q] = h8[(size_t)s[q] * 16 + l16];
#pragma unroll
        for (int q = 0; q < 8; ++q) {
            float4 v = h4_to_f4(r[q]);
            inner.x += v.x; inner.y += v.y; inner.z += v.z; inner.w += v.w;
        }
    }
    for (; j + 3 < end; j += 4) {
        int s0 = csr[j], s1 = csr[j + 1], s2 = csr[j + 2], s3 = csr[j + 3];
        float4 v0 = h4_to_f4(h8[(size_t)s0 * 16 + l16]);
        float4 v1 = h4_to_f4(h8[(size_t)s1 * 16 + l16]);
        float4 v2 = h4_to_f4(h8[(size_t)s2 * 16 + l16]);
        float4 v3 = h4_to_f4(h8[(size_t)s3 * 16 + l16]);
        inner.x += v0.x + v1.x + v2.x + v3.x;
        inner.y += v0.y + v1.y + v2.y + v3.y;
        inner.z += v0.z + v1.z + v2.z + v3.z;
        inner.w += v0.w + v1.w + v2.w + v3.w;
    }
    for (; j < end; j++) {
        float4 v = h4_to_f4(h8[(size_t)csr[j] * 16 + l16]);
        inner.x += v.x; inner.y += v.y; inner.z += v.z; inner.w += v.w;
    }
    float4 bb = b4[l16];
    __half2 q0 = __floats2half2_rn(bb.x + dv * inner.x, bb.y + dv * inner.y);
    __half2 q1 = __floats2half2_rn(bb.z + dv * inner.z, bb.w + dv * inner.w);
    int2 outv;
    outv.x = *(int*)&q0;
    outv.y = *(int*)&q1;
    ((int2*)agg)[(size_t)node * 16 + l16] = outv;
}

// ---- fused mean-pool + head: one block per graph, batch sorted ----------

__global__ __launch_bounds__(256) void k_pool_head(
        const __half* __restrict__ agg, const int* __restrict__ batch,
        const float* __restrict__ Wl, const float* __restrict__ bl,
        float* __restrict__ out, int n_nodes) {
    int g = blockIdx.x;
    int lo = 0, hi = n_nodes;
    while (lo < hi) { int m = (lo + hi) >> 1; if (batch[m] < g) lo = m + 1; else hi = m; }
    int nstart = lo;
    hi = n_nodes;
    while (lo < hi) { int m = (lo + hi) >> 1; if (batch[m] < g + 1) lo = m + 1; else hi = m; }
    int nend = lo;

    int c = threadIdx.x & 63, part = threadIdx.x >> 6;
    float acc = 0.0f;
    for (int n = nstart + part; n < nend; n += 4)
        acc += __half2float(agg[(size_t)n * HID + c]);

    __shared__ float red[4][64];
    __shared__ float hd[128];
    red[part][c] = acc;
    __syncthreads();
    if (threadIdx.x < 64) {
        float cntf = (float)(nend - nstart);
        float pooled = (red[0][c] + red[1][c] + red[2][c] + red[3][c])
                       / fmaxf(cntf, 1.0f);
        hd[c] = pooled * Wl[c * 2 + 0];
        hd[64 + c] = pooled * Wl[c * 2 + 1];
    }
    __syncthreads();
    if (threadIdx.x < 2) {
        float s = 0.0f;
        for (int k = 0; k < 64; k++) s += hd[threadIdx.x * 64 + k];
        out[g * 2 + threadIdx.x] = s + bl[threadIdx.x];
    }
}

// -------------------------------------------------------------------------

extern "C" void kernel_launch(void* const* d_in, const int* in_sizes, int n_in,
                              void* d_out, int out_size, void* d_ws, size_t ws_size,
                              hipStream_t stream) {
    const float* x     = (const float*)d_in[0];
    const int*   ei    = (const int*)d_in[1];
    const int*   batch = (const int*)d_in[2];
    const float* W1    = (const float*)d_in[3];
    const float* b1    = (const float*)d_in[4];
    const float* W2    = (const float*)d_in[5];
    const float* b2    = (const float*)d_in[6];
    const float* W3    = (const float*)d_in[7];
    const float* b3    = (const float*)d_in[8];
    const float* Wl    = (const float*)d_in[9];
    const float* bl    = (const float*)d_in[10];
    float* out = (float*)d_out;

    const int N = in_sizes[0] / 7;     // 100000
    const int E = in_sizes[1] / 2;     // 1250000
    const int* src = ei;
    const int* dst = ei + E;

    const int nbkt   = (N + BKTSZ - 1) >> BKTSH;          // 196
    const int nchunk = (E + CHUNK - 1) / CHUNK;           // 153
    const int lenH   = nbkt * nchunk;

    char* ws = (char*)d_ws;
    size_t off = 0;
    auto carve = [&](size_t bytes) {
        void* p = ws + off;
        off = (off + bytes + 255) & ~(size_t)255;
        return p;
    };
    int*    H      = (int*)carve((size_t)lenH * 4);
    int*    packed = (int*)carve((size_t)lenH * CAP * 4);   // ~15.4 MB
    int*    csr    = (int*)carve((size_t)E * 4);
    int*    rowptr = (int*)carve((size_t)(N + 1) * 4);
    float*  dinv   = (float*)carve((size_t)N * 4);
    __half* Wf2    = (__half*)carve(4096 * 2);
    __half* Wf3    = (__half*)carve(4096 * 2);
    __half* bufH   = (__half*)carve((size_t)(N + 64) * HID * 2);  // +pad rows
    __half* bufB   = (__half*)carve((size_t)(N + 64) * HID * 2);

    const int nb_gemm7 = (N + 15) / 16;    // 6250
    const int nb_agg   = (N + 15) / 16;    // 6250

    // ---- CSR build: fused scatter+hist, then per-bucket build
    k_scatter_hist<<<nchunk, 256, 0, stream>>>(src, dst, W2, W3, Wf2, Wf3,
                                               packed, H, E, nbkt, nchunk);
    k_csr_build<<<nbkt, 256, 0, stream>>>(packed, H, rowptr, dinv, csr,
                                          E, N, nbkt, nchunk);

    // ---- layer 1 gemm; fused agg+gemm x2; layer-3 aggregate
    k_gemm7<<<nb_gemm7, 256, 0, stream>>>(x, W1, dinv, bufH, N);
    k_agg_gemm<<<nb_agg, 256, 0, stream>>>(rowptr, csr, bufH, b1, dinv, Wf2, bufB, N);
    k_agg_gemm<<<nb_agg, 256, 0, stream>>>(rowptr, csr, bufB, b2, dinv, Wf3, bufH, N);
    k_aggregate<<<nb_agg, 256, 0, stream>>>(rowptr, csr, bufH, b3, dinv, bufB, N);

    // ---- fused mean-pool + head (one block per graph)
    k_pool_head<<<NGRAPHS, 256, 0, stream>>>(bufB, batch, Wl, bl, out, N);
}

// Round 19
// 257.562 us; speedup vs baseline: 1.1229x; 1.1229x over previous
//
#include <hip/hip_runtime.h>
#include <hip/hip_fp16.h>

#define HID 64
#define NGRAPHS 256
#define CHUNK 8192        // edges per pass-1 chunk
#define BKTSZ 512         // nodes per coarse bucket
#define BKTSH 9
#define PSH 17            // src fits in 17 bits (N <= 131072)
#define PMASK 0x1FFFF

typedef _Float16 half8 __attribute__((ext_vector_type(8)));
typedef float f32x4 __attribute__((ext_vector_type(4)));

// MEASURED LAWS (R1-R18):
//  - scattered device-scope atomics/stores write through ~64B lines at
//    ~0.9 TB/s; same-line fp32 atomics ~15 G/s -> LDS counting-sort CSR.
//  - grid.sync() coop barrier ~100us at full grid (R13) -> discrete
//    launches (~6-7us/boundary) are strictly cheaper here.
//  - R14: narrow-grid fusion serializes wide phases; R17: same-grid
//    fusion (agg+gemm) wins. R15: >8-wide gather unroll regresses.
//  - R18: slot-packed scatter + per-edge binary-search rebuild (60us)
//    loses to the 3-pass scan pipeline (25+5+7us). Keep the scan.

// ---- P0: prepW (blocks 0-1) + per-chunk coarse histogram ----------------

__global__ __launch_bounds__(256) void k_hist(
        const int* __restrict__ dst, const float* __restrict__ W2,
        const float* __restrict__ W3, __half* __restrict__ Wf2,
        __half* __restrict__ Wf3, int* __restrict__ H,
        int e, int nbkt, int nchunk) {
    __shared__ int cnt[256];
    const int t = threadIdx.x, b = blockIdx.x;
    const int gtid = b * 256 + t;
    if (gtid < 512) {       // W fragment repack: 16x16x32-f16 B layout
        int p = gtid;
        int kt = p >> 8, c = (p >> 6) & 3, lane = p & 63;
        int quad = lane >> 4, m = lane & 15;
#pragma unroll
        for (int j = 0; j < 8; ++j) {
            int k = kt * 32 + quad * 8 + j;
            int ch = c * 16 + m;
            Wf2[(size_t)p * 8 + j] = __float2half(W2[k * HID + ch]);
            Wf3[(size_t)p * 8 + j] = __float2half(W3[k * HID + ch]);
        }
    }
    for (int i = t; i < nbkt; i += 256) cnt[i] = 0;
    __syncthreads();
#pragma unroll
    for (int it = 0; it < CHUNK / 1024; ++it) {
        int idx = b * CHUNK + it * 1024 + t * 4;
        if (idx + 3 < e) {
            int4 d = *(const int4*)(dst + idx);
            atomicAdd(&cnt[d.x >> BKTSH], 1);
            atomicAdd(&cnt[d.y >> BKTSH], 1);
            atomicAdd(&cnt[d.z >> BKTSH], 1);
            atomicAdd(&cnt[d.w >> BKTSH], 1);
        } else {
            for (int i = idx; i < e && i < idx + 4; ++i)
                atomicAdd(&cnt[dst[i] >> BKTSH], 1);
        }
    }
    __syncthreads();
    for (int i = t; i < nbkt; i += 256) H[i * nchunk + b] = cnt[i];
}

// ---- P1: per-1024 partial exclusive scans + block sums ------------------

__global__ __launch_bounds__(256) void k_scan(const int* __restrict__ in,
                                              int* __restrict__ outp,
                                              int* __restrict__ bsum, int n) {
    __shared__ int sh[256];
    const int t = threadIdx.x;
    const int base = blockIdx.x * 1024 + t * 4;
    int v[4];
    int s = 0;
#pragma unroll
    for (int k = 0; k < 4; k++) {
        int i = base + k;
        v[k] = (i < n) ? in[i] : 0;
        s += v[k];
    }
    sh[t] = s;
    __syncthreads();
#pragma unroll
    for (int off = 1; off < 256; off <<= 1) {
        int add = (t >= off) ? sh[t - off] : 0;
        __syncthreads();
        sh[t] += add;
        __syncthreads();
    }
    int run = sh[t] - s;
#pragma unroll
    for (int k = 0; k < 4; k++) {
        int i = base + k;
        if (i < n) outp[i] = run;
        run += v[k];
    }
    if (t == 255) bsum[blockIdx.x] = sh[255];
}

// ---- P2: bucket scatter (packed 4B, coalesced runs) ---------------------

__global__ __launch_bounds__(256) void k_scatter(
        const int* __restrict__ src, const int* __restrict__ dst,
        const int* __restrict__ Hs, const int* __restrict__ bsum,
        int* __restrict__ packed, int e, int nbkt, int nchunk, int nscan) {
    __shared__ int off[256];
    __shared__ int lc[256];
    __shared__ int bpref[32];
    const int t = threadIdx.x, b = blockIdx.x;
    if (t == 0) {
        int run = 0;
        for (int i = 0; i < nscan; ++i) { bpref[i] = run; run += bsum[i]; }
    }
    __syncthreads();
    for (int i = t; i < nbkt; i += 256) {
        int idx = i * nchunk + b;
        off[i] = Hs[idx] + bpref[idx >> 10];
        lc[i] = 0;
    }
    __syncthreads();
#pragma unroll
    for (int it = 0; it < CHUNK / 1024; ++it) {
        int idx = b * CHUNK + it * 1024 + t * 4;
        if (idx + 3 < e) {
            int4 d = *(const int4*)(dst + idx);
            int4 s = *(const int4*)(src + idx);
            int b0 = d.x >> BKTSH, b1 = d.y >> BKTSH;
            int b2 = d.z >> BKTSH, b3 = d.w >> BKTSH;
            int r0 = atomicAdd(&lc[b0], 1);
            int r1 = atomicAdd(&lc[b1], 1);
            int r2 = atomicAdd(&lc[b2], 1);
            int r3 = atomicAdd(&lc[b3], 1);
            packed[off[b0] + r0] = s.x | ((d.x & (BKTSZ - 1)) << PSH);
            packed[off[b1] + r1] = s.y | ((d.y & (BKTSZ - 1)) << PSH);
            packed[off[b2] + r2] = s.z | ((d.z & (BKTSZ - 1)) << PSH);
            packed[off[b3] + r3] = s.w | ((d.w & (BKTSZ - 1)) << PSH);
        } else {
            for (int i = idx; i < e && i < idx + 4; ++i) {
                int dd = dst[i];
                int bk = dd >> BKTSH;
                int r = atomicAdd(&lc[bk], 1);
                packed[off[bk] + r] = src[i] | ((dd & (BKTSZ - 1)) << PSH);
            }
        }
    }
}

// ---- P3: per-bucket local CSR build (196 blocks, CSR work ONLY) ---------

__global__ __launch_bounds__(256) void k_csr_build(
        const int* __restrict__ packed, const int* __restrict__ Hs,
        const int* __restrict__ bsum, int* __restrict__ rowptr,
        float* __restrict__ dinv, int* __restrict__ csr,
        int e, int n, int nbkt, int nchunk, int nscan) {
    __shared__ int cnt[BKTSZ];
    __shared__ int pref[BKTSZ];
    __shared__ int ssum[256];
    __shared__ int cnt2[BKTSZ];
    __shared__ int bpref[32];
    const int t = threadIdx.x, bkt = blockIdx.x;
    if (t == 0) {
        int run = 0;
        for (int i = 0; i < nscan; ++i) { bpref[i] = run; run += bsum[i]; }
    }
    if (bkt == 0 && t == 0) rowptr[n] = e;
    cnt[t] = 0; cnt[t + 256] = 0;
    cnt2[t] = 0; cnt2[t + 256] = 0;
    __syncthreads();
    int i0 = bkt * nchunk;
    int segStart = Hs[i0] + bpref[i0 >> 10];
    int segEnd = e;
    if (bkt + 1 < nbkt) {
        int i1 = (bkt + 1) * nchunk;
        segEnd = Hs[i1] + bpref[i1 >> 10];
    }
    for (int j = segStart + t; j < segEnd; j += 256)
        atomicAdd(&cnt[(packed[j] >> PSH) & (BKTSZ - 1)], 1);
    __syncthreads();
    int a0 = cnt[2 * t], a1 = cnt[2 * t + 1];
    int s = a0 + a1;
    ssum[t] = s;
    __syncthreads();
#pragma unroll
    for (int off = 1; off < 256; off <<= 1) {
        int add = (t >= off) ? ssum[t - off] : 0;
        __syncthreads();
        ssum[t] += add;
        __syncthreads();
    }
    int p = ssum[t] - s;
    pref[2 * t] = p;
    pref[2 * t + 1] = p + a0;
    __syncthreads();
    for (int i = t; i < BKTSZ; i += 256) {
        int node = bkt * BKTSZ + i;
        if (node < n) {
            rowptr[node] = segStart + pref[i];
            dinv[node] = rsqrtf((float)(cnt[i] + 1));   // +1 self-loop
        }
    }
    for (int j = segStart + t; j < segEnd; j += 256) {
        int pk = packed[j];
        int ld = (pk >> PSH) & (BKTSZ - 1);
        int r = atomicAdd(&cnt2[ld], 1);
        csr[segStart + pref[ld] + r] = pk & PMASK;
    }
}

// ---- layer-1 gemm (K=7, fp32 in, WIDE grid): h' = (x @ W1) * dinv -------

__global__ __launch_bounds__(256) void k_gemm7(
        const float* __restrict__ act, const float* __restrict__ W,
        const float* __restrict__ dinv, __half* __restrict__ h, int n_nodes) {
    __shared__ float Wsh[7 * HID];
    __shared__ float Ash[16 * 7];
    const int t = threadIdx.x;
    const int n0 = blockIdx.x * 16;

    for (int i = t; i < 7 * HID; i += 256) Wsh[i] = W[i];
    const long long lim = (long long)(n_nodes - n0) * 7;
    for (int i = t; i < 16 * 7; i += 256)
        Ash[i] = (i < lim) ? act[(size_t)n0 * 7 + i] : 0.0f;
    __syncthreads();

    const int c = t & 63;
    const int g = t >> 6;
    float acc[4] = {0.0f, 0.0f, 0.0f, 0.0f};
#pragma unroll
    for (int k = 0; k < 7; k++) {
        float w = Wsh[k * HID + c];
#pragma unroll
        for (int i = 0; i < 4; i++) acc[i] += Ash[(g * 4 + i) * 7 + k] * w;
    }
#pragma unroll
    for (int i = 0; i < 4; i++) {
        int n = n0 + g * 4 + i;
        if (n < n_nodes) h[(size_t)n * HID + c] = __float2half(acc[i] * dinv[n]);
    }
}

__device__ __forceinline__ float4 h4_to_f4(int2 raw) {
    __half2 p0 = *(__half2*)&raw.x;
    __half2 p1 = *(__half2*)&raw.y;
    float2 f0 = __half22float2(p0);
    float2 f1 = __half22float2(p1);
    return make_float4(f0.x, f0.y, f1.x, f1.y);
}

// ---- FUSED aggregate + MFMA gemm (layers 1->2, 2->3) --------------------
// Block = 16 nodes. Aggregate (8-wide gathers, b+dv*inner), relu, stage
// act tile in LDS (stride 72 halves: pads b128 reads to 2-way-free), then
// each wave MFMAs its 16-out-ch slice: hout = (act @ Wf) * dinv. Same wide
// grid as plain aggregate (R14 lesson); saves the agg buffer round-trip.

__global__ __launch_bounds__(256) void k_agg_gemm(
        const int* __restrict__ rowptr, const int* __restrict__ csr,
        const __half* __restrict__ h, const float* __restrict__ b,
        const float* __restrict__ dinv, const __half* __restrict__ Wf,
        __half* __restrict__ hout, int n_nodes) {
    __shared__ __half act[16 * 72];
    const int t = threadIdx.x;
    const int n0 = blockIdx.x * 16;
    const int nl = t >> 4;          // local node 0..15
    const int node = n0 + nl;
    const int l16 = t & 15;
    const int2* h8 = (const int2*)h;
    const float4* b4 = (const float4*)b;

    float4 av = make_float4(0.0f, 0.0f, 0.0f, 0.0f);
    if (node < n_nodes) {
        int beg = rowptr[node], end = rowptr[node + 1];
        float dv = dinv[node];
        float4 inner = h4_to_f4(h8[(size_t)node * 16 + l16]);   // self h'
        int j = beg;
        for (; j + 7 < end; j += 8) {              // 8 outstanding gathers
            int s[8];
#pragma unroll
            for (int q = 0; q < 8; ++q) s[q] = csr[j + q];
            int2 r[8];
#pragma unroll
            for (int q = 0; q < 8; ++q) r[q] = h8[(size_t)s[q] * 16 + l16];
#pragma unroll
            for (int q = 0; q < 8; ++q) {
                float4 v = h4_to_f4(r[q]);
                inner.x += v.x; inner.y += v.y; inner.z += v.z; inner.w += v.w;
            }
        }
        for (; j + 3 < end; j += 4) {
            int s0 = csr[j], s1 = csr[j + 1], s2 = csr[j + 2], s3 = csr[j + 3];
            float4 v0 = h4_to_f4(h8[(size_t)s0 * 16 + l16]);
            float4 v1 = h4_to_f4(h8[(size_t)s1 * 16 + l16]);
            float4 v2 = h4_to_f4(h8[(size_t)s2 * 16 + l16]);
            float4 v3 = h4_to_f4(h8[(size_t)s3 * 16 + l16]);
            inner.x += v0.x + v1.x + v2.x + v3.x;
            inner.y += v0.y + v1.y + v2.y + v3.y;
            inner.z += v0.z + v1.z + v2.z + v3.z;
            inner.w += v0.w + v1.w + v2.w + v3.w;
        }
        for (; j < end; j++) {
            float4 v = h4_to_f4(h8[(size_t)csr[j] * 16 + l16]);
            inner.x += v.x; inner.y += v.y; inner.z += v.z; inner.w += v.w;
        }
        float4 bb = b4[l16];
        av.x = fmaxf(bb.x + dv * inner.x, 0.0f);   // relu(agg) = gemm input
        av.y = fmaxf(bb.y + dv * inner.y, 0.0f);
        av.z = fmaxf(bb.z + dv * inner.z, 0.0f);
        av.w = fmaxf(bb.w + dv * inner.w, 0.0f);
    }
    {   // stage act tile: row nl, cols l16*4..+3 (8B store)
        __half2 p0 = __floats2half2_rn(av.x, av.y);
        __half2 p1 = __floats2half2_rn(av.z, av.w);
        int2 pk;
        pk.x = *(int*)&p0;
        pk.y = *(int*)&p1;
        *(int2*)&act[nl * 72 + l16 * 4] = pk;
    }
    __syncthreads();

    const int wave = t >> 6, lane = t & 63;
    const int quad = lane >> 4, m = lane & 15;
    const half8* Wf8 = (const half8*)Wf;
    f32x4 acc = {0.0f, 0.0f, 0.0f, 0.0f};
#pragma unroll
    for (int kt = 0; kt < 2; ++kt) {
        half8 a = *(const half8*)&act[m * 72 + kt * 32 + quad * 8];
        half8 bv = Wf8[(kt * 4 + wave) * 64 + lane];
        acc = __builtin_amdgcn_mfma_f32_16x16x32_f16(a, bv, acc, 0, 0, 0);
    }
#pragma unroll
    for (int r = 0; r < 4; ++r) {
        int nd = n0 + quad * 4 + r;
        if (nd < n_nodes)
            hout[(size_t)nd * HID + wave * 16 + m] =
                __float2half(acc[r] * dinv[nd]);
    }
}

// ---- layer-3 aggregate (standalone; pool needs agg), fp16 out -----------

__global__ __launch_bounds__(256) void k_aggregate(
        const int* __restrict__ rowptr, const int* __restrict__ csr,
        const __half* __restrict__ h, const float* __restrict__ b,
        const float* __restrict__ dinv, __half* __restrict__ agg, int n_nodes) {
    int node = blockIdx.x * 16 + (threadIdx.x >> 4);
    int l16 = threadIdx.x & 15;
    if (node >= n_nodes) return;
    int beg = rowptr[node], end = rowptr[node + 1];
    const int2* h8 = (const int2*)h;
    const float4* b4 = (const float4*)b;
    float dv = dinv[node];
    float4 inner = h4_to_f4(h8[(size_t)node * 16 + l16]);   // self h'
    int j = beg;
    for (; j + 7 < end; j += 8) {                  // 8 outstanding gathers
        int s[8];
#pragma unroll
        for (int q = 0; q < 8; ++q) s[q] = csr[j + q];
        int2 r[8];
#pragma unroll
        for (int q = 0; q < 8; ++q) r[q] = h8[(size_t)s[q] * 16 + l16];
#pragma unroll
        for (int q = 0; q < 8; ++q) {
            float4 v = h4_to_f4(r[q]);
            inner.x += v.x; inner.y += v.y; inner.z += v.z; inner.w += v.w;
        }
    }
    for (; j + 3 < end; j += 4) {
        int s0 = csr[j], s1 = csr[j + 1], s2 = csr[j + 2], s3 = csr[j + 3];
        float4 v0 = h4_to_f4(h8[(size_t)s0 * 16 + l16]);
        float4 v1 = h4_to_f4(h8[(size_t)s1 * 16 + l16]);
        float4 v2 = h4_to_f4(h8[(size_t)s2 * 16 + l16]);
        float4 v3 = h4_to_f4(h8[(size_t)s3 * 16 + l16]);
        inner.x += v0.x + v1.x + v2.x + v3.x;
        inner.y += v0.y + v1.y + v2.y + v3.y;
        inner.z += v0.z + v1.z + v2.z + v3.z;
        inner.w += v0.w + v1.w + v2.w + v3.w;
    }
    for (; j < end; j++) {
        float4 v = h4_to_f4(h8[(size_t)csr[j] * 16 + l16]);
        inner.x += v.x; inner.y += v.y; inner.z += v.z; inner.w += v.w;
    }
    float4 bb = b4[l16];
    __half2 q0 = __floats2half2_rn(bb.x + dv * inner.x, bb.y + dv * inner.y);
    __half2 q1 = __floats2half2_rn(bb.z + dv * inner.z, bb.w + dv * inner.w);
    int2 outv;
    outv.x = *(int*)&q0;
    outv.y = *(int*)&q1;
    ((int2*)agg)[(size_t)node * 16 + l16] = outv;
}

// ---- fused mean-pool + head: one block per graph, batch sorted ----------

__global__ __launch_bounds__(256) void k_pool_head(
        const __half* __restrict__ agg, const int* __restrict__ batch,
        const float* __restrict__ Wl, const float* __restrict__ bl,
        float* __restrict__ out, int n_nodes) {
    int g = blockIdx.x;
    int lo = 0, hi = n_nodes;
    while (lo < hi) { int m = (lo + hi) >> 1; if (batch[m] < g) lo = m + 1; else hi = m; }
    int nstart = lo;
    hi = n_nodes;
    while (lo < hi) { int m = (lo + hi) >> 1; if (batch[m] < g + 1) lo = m + 1; else hi = m; }
    int nend = lo;

    int c = threadIdx.x & 63, part = threadIdx.x >> 6;
    float acc = 0.0f;
    for (int n = nstart + part; n < nend; n += 4)
        acc += __half2float(agg[(size_t)n * HID + c]);

    __shared__ float red[4][64];
    __shared__ float hd[128];
    red[part][c] = acc;
    __syncthreads();
    if (threadIdx.x < 64) {
        float cntf = (float)(nend - nstart);
        float pooled = (red[0][c] + red[1][c] + red[2][c] + red[3][c])
                       / fmaxf(cntf, 1.0f);
        hd[c] = pooled * Wl[c * 2 + 0];
        hd[64 + c] = pooled * Wl[c * 2 + 1];
    }
    __syncthreads();
    if (threadIdx.x < 2) {
        float s = 0.0f;
        for (int k = 0; k < 64; k++) s += hd[threadIdx.x * 64 + k];
        out[g * 2 + threadIdx.x] = s + bl[threadIdx.x];
    }
}

// -------------------------------------------------------------------------

extern "C" void kernel_launch(void* const* d_in, const int* in_sizes, int n_in,
                              void* d_out, int out_size, void* d_ws, size_t ws_size,
                              hipStream_t stream) {
    const float* x     = (const float*)d_in[0];
    const int*   ei    = (const int*)d_in[1];
    const int*   batch = (const int*)d_in[2];
    const float* W1    = (const float*)d_in[3];
    const float* b1    = (const float*)d_in[4];
    const float* W2    = (const float*)d_in[5];
    const float* b2    = (const float*)d_in[6];
    const float* W3    = (const float*)d_in[7];
    const float* b3    = (const float*)d_in[8];
    const float* Wl    = (const float*)d_in[9];
    const float* bl    = (const float*)d_in[10];
    float* out = (float*)d_out;

    const int N = in_sizes[0] / 7;     // 100000
    const int E = in_sizes[1] / 2;     // 1250000
    const int* src = ei;
    const int* dst = ei + E;

    const int nbkt   = (N + BKTSZ - 1) >> BKTSH;          // 196
    const int nchunk = (E + CHUNK - 1) / CHUNK;           // 153
    const int lenH   = nbkt * nchunk;
    const int nscan  = (lenH + 1023) / 1024;              // 30 (<=32)

    char* ws = (char*)d_ws;
    size_t off = 0;
    auto carve = [&](size_t bytes) {
        void* p = ws + off;
        off = (off + bytes + 255) & ~(size_t)255;
        return p;
    };
    int*    H      = (int*)carve((size_t)lenH * 4);
    int*    Hs     = (int*)carve((size_t)lenH * 4);
    int*    bsum   = (int*)carve(512 * 4);
    int*    packed = (int*)carve((size_t)E * 4);
    int*    csr    = (int*)carve((size_t)E * 4);
    int*    rowptr = (int*)carve((size_t)(N + 1) * 4);
    float*  dinv   = (float*)carve((size_t)N * 4);
    __half* Wf2    = (__half*)carve(4096 * 2);
    __half* Wf3    = (__half*)carve(4096 * 2);
    __half* bufH   = (__half*)carve((size_t)(N + 64) * HID * 2);  // +pad rows
    __half* bufB   = (__half*)carve((size_t)(N + 64) * HID * 2);

    const int nb_gemm7 = (N + 15) / 16;    // 6250
    const int nb_agg   = (N + 15) / 16;    // 6250

    // ---- CSR build (LDS counting sort, 3-pass scan pipeline)
    k_hist<<<nchunk, 256, 0, stream>>>(dst, W2, W3, Wf2, Wf3, H, E, nbkt, nchunk);
    k_scan<<<nscan, 256, 0, stream>>>(H, Hs, bsum, lenH);
    k_scatter<<<nchunk, 256, 0, stream>>>(src, dst, Hs, bsum, packed,
                                          E, nbkt, nchunk, nscan);
    k_csr_build<<<nbkt, 256, 0, stream>>>(packed, Hs, bsum, rowptr, dinv, csr,
                                          E, N, nbkt, nchunk, nscan);

    // ---- layer 1 gemm; fused agg+gemm x2; layer-3 aggregate
    k_gemm7<<<nb_gemm7, 256, 0, stream>>>(x, W1, dinv, bufH, N);
    k_agg_gemm<<<nb_agg, 256, 0, stream>>>(rowptr, csr, bufH, b1, dinv, Wf2, bufB, N);
    k_agg_gemm<<<nb_agg, 256, 0, stream>>>(rowptr, csr, bufB, b2, dinv, Wf3, bufH, N);
    k_aggregate<<<nb_agg, 256, 0, stream>>>(rowptr, csr, bufH, b3, dinv, bufB, N);

    // ---- fused mean-pool + head (one block per graph)
    k_pool_head<<<NGRAPHS, 256, 0, stream>>>(bufB, batch, Wl, bl, out, N);
}